// Round 1
// baseline (343.198 us; speedup 1.0000x reference)
//
#include <hip/hip_runtime.h>
#include <math.h>

#define SEMEME_SIZE 2048
#define D_MODEL 512
#define BLOCK 256

// One block per token.
// Phase 1: coalesced scan of word2sememe[x[token]] (2048 fp32), collect
//          nonzero (index, value) pairs into LDS, reduce the row sum.
// Phase 2: out[token][d] = scale * sum_i val[i] * W[idx[i]][d],
//          scale = sqrt(512) / (rowsum + 1e-6). Each thread does d = tid
//          and d = tid + 256 (D_MODEL = 2 * BLOCK).
__global__ __launch_bounds__(BLOCK) void sememe_embed_kernel(
    const int* __restrict__ x,
    const float* __restrict__ w2s,
    const float* __restrict__ W,
    float* __restrict__ out)
{
    __shared__ int   s_idx[SEMEME_SIZE];
    __shared__ float s_val[SEMEME_SIZE];
    __shared__ int   s_nnz;
    __shared__ float s_sum;

    const int token = blockIdx.x;
    const int tid   = threadIdx.x;

    if (tid == 0) { s_nnz = 0; s_sum = 0.0f; }
    __syncthreads();

    const long long wid = (long long)x[token];
    const float4* row4 = (const float4*)(w2s + (size_t)wid * SEMEME_SIZE);

    float local_sum = 0.0f;
    // 2048 floats / 4 per float4 / 256 threads = 2 float4 per thread
    #pragma unroll
    for (int c = 0; c < SEMEME_SIZE / 4 / BLOCK; ++c) {
        const int q = c * BLOCK + tid;          // float4 index within row
        const float4 v = row4[q];
        const float vv[4] = { v.x, v.y, v.z, v.w };
        #pragma unroll
        for (int j = 0; j < 4; ++j) {
            if (vv[j] != 0.0f) {
                const int slot = atomicAdd(&s_nnz, 1);
                s_idx[slot] = q * 4 + j;
                s_val[slot] = vv[j];
                local_sum += vv[j];
            }
        }
    }

    // wave-64 shuffle reduction, then one LDS atomic per wave
    #pragma unroll
    for (int off = 32; off > 0; off >>= 1)
        local_sum += __shfl_down(local_sum, off, 64);
    if ((tid & 63) == 0) atomicAdd(&s_sum, local_sum);
    __syncthreads();

    const int nnz = s_nnz;
    const float scale = 22.62741699796952f / (s_sum + 1e-6f);  // sqrt(512)/(sum+eps)

    float acc0 = 0.0f, acc1 = 0.0f;
    for (int i = 0; i < nnz; ++i) {
        const int k = s_idx[i];
        const float v = s_val[i];
        const float* __restrict__ wr = W + (size_t)k * D_MODEL;
        acc0 += v * wr[tid];
        acc1 += v * wr[tid + BLOCK];
    }

    float* __restrict__ o = out + (size_t)token * D_MODEL;
    o[tid]         = acc0 * scale;
    o[tid + BLOCK] = acc1 * scale;
}

extern "C" void kernel_launch(void* const* d_in, const int* in_sizes, int n_in,
                              void* d_out, int out_size, void* d_ws, size_t ws_size,
                              hipStream_t stream) {
    const int*   x   = (const int*)d_in[0];     // [B*S] token ids
    const float* w2s = (const float*)d_in[1];   // [VOCAB, SEMEME_SIZE]
    const float* W   = (const float*)d_in[2];   // [SEMEME_SIZE, D_MODEL]
    float* out = (float*)d_out;                 // [B*S, D_MODEL]

    const int n_tokens = in_sizes[0];           // 16384

    sememe_embed_kernel<<<n_tokens, BLOCK, 0, stream>>>(x, w2s, W, out);
}